// Round 16
// baseline (221.276 us; speedup 1.0000x reference)
//
#include <hip/hip_runtime.h>
#include <hip/hip_bf16.h>

typedef __attribute__((ext_vector_type(8))) short bf16x8;
typedef __attribute__((ext_vector_type(4))) float f32x4;
typedef __attribute__((ext_vector_type(4))) unsigned short us4;

#define MFMA16(a,b,c) __builtin_amdgcn_mfma_f32_16x16x32_bf16((a),(b),(c),0,0,0)

__device__ __forceinline__ unsigned short f2bf(float f){
  unsigned u = __builtin_bit_cast(unsigned, f);
  u += 0x7fffu + ((u>>16)&1u);
  return (unsigned short)(u>>16);
}
__device__ __forceinline__ float bf2f(unsigned short h){
  unsigned u = ((unsigned)h)<<16;
  return __builtin_bit_cast(float, u);
}
__device__ __forceinline__ void gload_lds16(const unsigned short* g, unsigned short* l){
  __builtin_amdgcn_global_load_lds((const __attribute__((address_space(1))) void*)g,
                                   (__attribute__((address_space(3))) void*)l,
                                   16, 0, 0);
}

// ---------------- cast fp32 -> bf16 (query, in_proj_w, out_proj_w) ----------------
__global__ __launch_bounds__(256) void cast_all(
    const float* __restrict__ q, const float* __restrict__ wi, const float* __restrict__ wo,
    unsigned short* __restrict__ qq, unsigned short* __restrict__ wib, unsigned short* __restrict__ wob)
{
  int i4 = (blockIdx.x*256 + threadIdx.x)*4;
  const float* src; unsigned short* dst; int off;
  if (i4 < 4194304)       { src=q;  dst=qq;  off=i4; }
  else if (i4 < 7340032)  { src=wi; dst=wib; off=i4-4194304; }
  else                    { src=wo; dst=wob; off=i4-7340032; }
  float4 v = *(const float4*)(src+off);
  us4 o; o.x=f2bf(v.x); o.y=f2bf(v.y); o.z=f2bf(v.z); o.w=f2bf(v.w);
  *(us4*)(dst+off) = o;
}

// ---------------- GEMM-BT 128x128, BK=64: qkv = query @ W_in^T + b -----------------
// 2D-chunked XCD placement (R15-verified).
__global__ __launch_bounds__(256) void gemm_qkv(
    const unsigned short* __restrict__ A, const unsigned short* __restrict__ Bw,
    const float* __restrict__ bias,
    unsigned short* __restrict__ qo, unsigned short* __restrict__ ko, unsigned short* __restrict__ vTo)
{
  __shared__ unsigned short lA[128*64];
  __shared__ unsigned short lB[128*64];
  int tid = threadIdx.x, lane = tid&63, w = tid>>6;
  int wr = (w>>1)<<6, wc = (w&1)<<6;
  int lin = blockIdx.y*24 + blockIdx.x;
  int xcd = lin & 7, idx = lin >> 3;          // 96 blocks per XCD
  int rg = xcd >> 1, cg = xcd & 1;
  int rowT = ((rg<<3) + (idx & 7)) << 7;      // row tile 0..31
  int colT = (cg*12 + (idx >> 3)) << 7;       // col tile 0..23
  f32x4 acc[4][4] = {};
  for (int k0=0; k0<1024; k0+=64){
    #pragma unroll
    for (int it=0; it<4; ++it){
      int ci = it*256+tid; int r=ci>>3, cs=ci&7;
      int c = (cs ^ (r&7))<<3;
      gload_lds16(A + (size_t)(rowT+r)*1024 + k0 + c, &lA[ci<<3]);
    }
    #pragma unroll
    for (int it=0; it<4; ++it){
      int ci = it*256+tid; int r=ci>>3, cs=ci&7;
      int c = (cs ^ (r&7))<<3;
      gload_lds16(Bw + (size_t)(colT+r)*1024 + k0 + c, &lB[ci<<3]);
    }
    asm volatile("s_waitcnt vmcnt(0)" ::: "memory");
    __syncthreads();
    #pragma unroll
    for (int kk=0; kk<2; ++kk){
      int kc = (kk<<2) + (lane>>4);
      bf16x8 a[4], b[4];
      #pragma unroll
      for (int i=0;i<4;++i){
        int r = wr + (i<<4) + (lane&15);
        a[i] = *(const bf16x8*)&lA[(r<<6) + ((kc ^ (r&7))<<3)];
      }
      #pragma unroll
      for (int j=0;j<4;++j){
        int r = wc + (j<<4) + (lane&15);
        b[j] = *(const bf16x8*)&lB[(r<<6) + ((kc ^ (r&7))<<3)];
      }
      #pragma unroll
      for (int i=0;i<4;++i)
        #pragma unroll
        for (int j=0;j<4;++j)
          acc[i][j] = MFMA16(a[i], b[j], acc[i][j]);
    }
    __syncthreads();
  }
  int sec = colT >> 10;
  #pragma unroll
  for (int i=0;i<4;++i){
    #pragma unroll
    for (int j=0;j<4;++j){
      int cg2 = colT + wc + (j<<4) + (lane&15);
      int d = cg2 & 1023, hh = d>>6, di = d&63;
      float bsv = bias[cg2];
      #pragma unroll
      for (int q=0;q<4;++q){
        int m = rowT + wr + (i<<4) + ((lane>>4)<<2) + q;
        int b = m>>10, n = m&1023;
        unsigned short bv = f2bf(acc[i][j][q] + bsv);
        size_t bh = (size_t)((b<<4) + hh);
        if (sec==0)      qo[(bh<<16) + ((size_t)n<<6) + di] = bv;
        else if (sec==1) ko[(bh<<16) + ((size_t)n<<6) + di] = bv;
        else             vTo[(bh<<16) + ((size_t)di<<10) + n] = bv;
      }
    }
  }
}

// ---------------- GEMM-BT 128x128: out = oa @ W_out^T + b (fp32 out) ----------------
// 2D-chunked XCD placement (R15-verified); nontemporal final stores (this round).
__global__ __launch_bounds__(256) void gemm_out(
    const unsigned short* __restrict__ A, const unsigned short* __restrict__ Bw,
    const float* __restrict__ bias, float* __restrict__ out)
{
  __shared__ unsigned short lA[128*64];
  __shared__ unsigned short lB[128*64];
  int tid = threadIdx.x, lane = tid&63, w = tid>>6;
  int wr = (w>>1)<<6, wc = (w&1)<<6;
  int lin = blockIdx.y*8 + blockIdx.x;
  int xcd = lin & 7, idx = lin >> 3;          // 32 blocks per XCD
  int rg = xcd >> 1, cg = xcd & 1;
  int rowT = ((rg<<3) + (idx & 7)) << 7;      // row tile 0..31
  int colT = ((cg<<2) + (idx >> 3)) << 7;     // col tile 0..7
  f32x4 acc[4][4] = {};
  for (int k0=0; k0<1024; k0+=64){
    #pragma unroll
    for (int it=0; it<4; ++it){
      int ci = it*256+tid; int r=ci>>3, cs=ci&7;
      int c = (cs ^ (r&7))<<3;
      gload_lds16(A + (size_t)(rowT+r)*1024 + k0 + c, &lA[ci<<3]);
    }
    #pragma unroll
    for (int it=0; it<4; ++it){
      int ci = it*256+tid; int r=ci>>3, cs=ci&7;
      int c = (cs ^ (r&7))<<3;
      gload_lds16(Bw + (size_t)(colT+r)*1024 + k0 + c, &lB[ci<<3]);
    }
    asm volatile("s_waitcnt vmcnt(0)" ::: "memory");
    __syncthreads();
    #pragma unroll
    for (int kk=0; kk<2; ++kk){
      int kc = (kk<<2) + (lane>>4);
      bf16x8 a[4], b[4];
      #pragma unroll
      for (int i=0;i<4;++i){
        int r = wr + (i<<4) + (lane&15);
        a[i] = *(const bf16x8*)&lA[(r<<6) + ((kc ^ (r&7))<<3)];
      }
      #pragma unroll
      for (int j=0;j<4;++j){
        int r = wc + (j<<4) + (lane&15);
        b[j] = *(const bf16x8*)&lB[(r<<6) + ((kc ^ (r&7))<<3)];
      }
      #pragma unroll
      for (int i=0;i<4;++i)
        #pragma unroll
        for (int j=0;j<4;++j)
          acc[i][j] = MFMA16(a[i], b[j], acc[i][j]);
    }
    __syncthreads();
  }
  #pragma unroll
  for (int i=0;i<4;++i){
    #pragma unroll
    for (int j=0;j<4;++j){
      int cg2 = colT + wc + (j<<4) + (lane&15);
      float bsv = bias[cg2];
      #pragma unroll
      for (int q=0;q<4;++q){
        int m = rowT + wr + (i<<4) + ((lane>>4)<<2) + q;
        __builtin_nontemporal_store(acc[i][j][q] + bsv, out + (size_t)m*1024 + cg2);
      }
    }
  }
}

// ---------------- fused attention: one WG = one (b,h) x 32-row stripe ----------------
// R12 version (C+D interleaved); this round: nontemporal attn_weights stores.
__global__ __launch_bounds__(256) void attn_fused(
    const unsigned short* __restrict__ qbf, const unsigned short* __restrict__ kbf,
    const unsigned short* __restrict__ vT, const float* __restrict__ tbl,
    float* __restrict__ attn_out, unsigned short* __restrict__ oa)
{
  __shared__ unsigned short P[32*1024];   // 64 KB, XOR-swizzled 16B chunks
  __shared__ unsigned short qs[32*64];    // 4 KB, swizzled
  __shared__ float biasv[64];
  __shared__ float rsum[4][32];
  __shared__ float rinv_s[32];

  int tid=threadIdx.x, lane=tid&63, w=tid>>6;
  int bid = blockIdx.x;
  int wgid = ((bid&7)<<8) + (bid>>3);     // XCD swizzle: 8 pairs per XCD -> K/V L2-resident
  int pair = wgid >> 5;                   // b*16 + h
  int stripe = wgid & 31;
  int h = pair & 15;
  int bg = pair >> 4;
  int nbase = stripe<<5;
  const unsigned short* qg = qbf + ((size_t)pair<<16) + ((size_t)nbase<<6);
  const unsigned short* kg = kbf + ((size_t)pair<<16);
  const unsigned short* vg = vT  + ((size_t)pair<<16);

  // per-head bias LUT over relative offset d in [-31,31]
  if (tid < 63){
    int dd = tid - 31;
    int neg = dd<0 ? 1:0;
    int a = dd<0 ? -dd : dd;
    int bkt;
    if (a<16) bkt = a;
    else bkt = 16 + (int)(__logf((float)a*(1.f/16.f)) * (16.f/__logf(8.f)));
    bkt += neg*32;
    biasv[tid] = tbl[(bkt<<4) + h];
  }
  // stage q stripe 32x64 (swizzled)
  { int r=tid>>3, cs=tid&7;
    int c = (cs ^ (r&7))<<3;
    gload_lds16(qg + (r<<6) + c, &qs[tid<<3]); }
  asm volatile("s_waitcnt vmcnt(0)" ::: "memory");
  __syncthreads();

  int x = lane&15, g = lane>>4;
  // col-term bias: 12 registers, loaded once (static indices -> stays in VGPRs)
  float cterm[3][4];
  #pragma unroll
  for (int s=0;s<3;++s)
    #pragma unroll
    for (int q=0;q<4;++q)
      cterm[s][q] = biasv[(g<<2) + q - x + 31 + ((s-1)<<4)];

  // hoisted Q fragments: invariant across the whole column loop
  bf16x8 qa[2][2];
  #pragma unroll
  for (int rt=0;rt<2;++rt){
    int r = (rt<<4) + x;
    #pragma unroll
    for (int hh=0;hh<2;++hh)
      qa[rt][hh] = *(const bf16x8*)&qs[(r<<6) + ((((hh<<2)+g) ^ (r&7))<<3)];
  }

  // phase B: logits -> exp -> P(bf16), per-wave 256-col slice
  float rs[2][4] = {};
  int colW = w<<8;
  for (int ct2=0; ct2<8; ++ct2){
    int cbb = colW + (ct2<<5);
    float rterm = biasv[stripe - (cbb>>5) + 31];   // wave-uniform row term
    #pragma unroll
    for (int par=0; par<2; ++par){
      int cb = cbb + (par<<4);
      int j = cb + x;
      const unsigned short* kp = kg + ((size_t)j<<6) + (g<<3);
      bf16x8 bk0 = *(const bf16x8*)kp;
      bf16x8 bk1 = *(const bf16x8*)(kp+32);
      #pragma unroll
      for (int rt=0; rt<2; ++rt){
        f32x4 acc = {};
        acc = MFMA16(qa[rt][0], bk0, acc);
        acc = MFMA16(qa[rt][1], bk1, acc);
        #pragma unroll
        for (int q=0;q<4;++q){
          int r = (rt<<4) + (g<<2) + q;
          float lg = acc[q]*0.125f + rterm + cterm[rt+1-par][q];
          float e = __expf(lg);
          rs[rt][q] += e;
          int byteoff = (r<<11) + ((((j>>3) ^ (r&7)))<<4) + ((j&7)<<1);
          *(unsigned short*)((char*)P + byteoff) = f2bf(e);
        }
      }
    }
  }
  // row sums: butterfly over 16 col-lanes, then cross-wave via LDS
  #pragma unroll
  for (int rt=0;rt<2;++rt){
    #pragma unroll
    for (int q=0;q<4;++q){
      float v = rs[rt][q];
      v += __shfl_xor(v,1); v += __shfl_xor(v,2); v += __shfl_xor(v,4); v += __shfl_xor(v,8);
      if (x==0) rsum[w][(rt<<4)+(g<<2)+q] = v;
    }
  }
  __syncthreads();
  if (tid<32) rinv_s[tid] = 1.f/(rsum[0][tid]+rsum[1][tid]+rsum[2][tid]+rsum[3][tid]);
  __syncthreads();

  // phases C+D interleaved over 8 column-blocks of 128
  float* ao = attn_out + ((size_t)pair<<20) + ((size_t)nbase<<10);
  f32x4 oacc[2] = {};
  int dbase = w<<4;
  const unsigned short* vp = vg + ((size_t)(dbase + x)<<10) + (g<<3);
  for (int cbk=0; cbk<8; ++cbk){
    // C slice: 32 rows x 128 cols, nontemporal stores (never re-read)
    #pragma unroll
    for (int it=0; it<2; ++it){
      int r = (it<<4) + (tid>>4);
      int c8 = (cbk<<7) + ((tid&15)<<3);
      int byteoff = (r<<11) + ((((c8>>3) ^ (r&7)))<<4);
      bf16x8 pv8 = *(const bf16x8*)((char*)P + byteoff);
      float ri = rinv_s[r];
      f32x4 o0, o1;
      o0.x = bf2f((unsigned short)pv8[0])*ri;
      o0.y = bf2f((unsigned short)pv8[1])*ri;
      o0.z = bf2f((unsigned short)pv8[2])*ri;
      o0.w = bf2f((unsigned short)pv8[3])*ri;
      o1.x = bf2f((unsigned short)pv8[4])*ri;
      o1.y = bf2f((unsigned short)pv8[5])*ri;
      o1.z = bf2f((unsigned short)pv8[6])*ri;
      o1.w = bf2f((unsigned short)pv8[7])*ri;
      __builtin_nontemporal_store(o0, (f32x4*)(ao + ((size_t)r<<10) + c8));
      __builtin_nontemporal_store(o1, (f32x4*)(ao + ((size_t)r<<10) + c8 + 4));
    }
    // D slice: 128 K-steps of PV
    #pragma unroll
    for (int ks=0; ks<4; ++ks){
      int kc = (cbk<<7) + (ks<<5);
      bf16x8 bv = *(const bf16x8*)(vp + kc);
      int ck = (kc>>3) + g;
      #pragma unroll
      for (int rt=0;rt<2;++rt){
        int r = (rt<<4) + x;
        bf16x8 a = *(const bf16x8*)((char*)P + (r<<11) + ((ck ^ (r&7))<<4));
        oacc[rt] = MFMA16(a, bv, oacc[rt]);
      }
    }
  }
  #pragma unroll
  for (int rt=0;rt<2;++rt){
    #pragma unroll
    for (int q=0;q<4;++q){
      int r = (rt<<4) + (g<<2) + q;
      float val = oacc[rt][q]*rinv_s[r];
      oa[((size_t)((bg<<10) + nbase + r)<<10) + (h<<6) + dbase + x] = f2bf(val);
    }
  }
}

extern "C" void kernel_launch(void* const* d_in, const int* in_sizes, int n_in,
                              void* d_out, int out_size, void* d_ws, size_t ws_size,
                              hipStream_t stream)
{
  const float* query = (const float*)d_in[0];
  const float* wi  = (const float*)d_in[3];
  const float* bi  = (const float*)d_in[4];
  const float* wo  = (const float*)d_in[5];
  const float* bo  = (const float*)d_in[6];
  const float* tbl = (const float*)d_in[7];

  char* ws = (char*)d_ws;
  unsigned short* qq  = (unsigned short*)(ws);              // query bf16   8 MB
  unsigned short* wib = (unsigned short*)(ws + 8388608);    // W_in bf16    6 MB
  unsigned short* wob = (unsigned short*)(ws + 14680064);   // W_out bf16   2 MB
  unsigned short* qbf = (unsigned short*)(ws + 16777216);   // q [B,H,N,hd] 8 MB
  unsigned short* kbf = (unsigned short*)(ws + 25165824);   // k [B,H,N,hd] 8 MB
  unsigned short* vTb = (unsigned short*)(ws + 33554432);   // vT [B,H,hd,N] 8 MB
  unsigned short* oa  = (unsigned short*)(ws + 41943040);   // out_attn bf16 8 MB

  float* out  = (float*)d_out;
  float* attn = out + 4194304;

  cast_all<<<dim3(8192), dim3(256), 0, stream>>>(query, wi, wo, qq, wib, wob);
  gemm_qkv<<<dim3(24,32), dim3(256), 0, stream>>>(qq, wib, bi, qbf, kbf, vTb);
  attn_fused<<<dim3(2048), dim3(256), 0, stream>>>(qbf, kbf, vTb, tbl, attn, oa);
  gemm_out<<<dim3(8,32), dim3(256), 0, stream>>>(oa, wob, bo, out);
}

// Round 17
// 188.058 us; speedup vs baseline: 1.1766x; 1.1766x over previous
//
#include <hip/hip_runtime.h>
#include <hip/hip_bf16.h>

typedef __attribute__((ext_vector_type(8))) short bf16x8;
typedef __attribute__((ext_vector_type(4))) float f32x4;
typedef __attribute__((ext_vector_type(4))) unsigned short us4;

#define MFMA16(a,b,c) __builtin_amdgcn_mfma_f32_16x16x32_bf16((a),(b),(c),0,0,0)

__device__ __forceinline__ unsigned short f2bf(float f){
  unsigned u = __builtin_bit_cast(unsigned, f);
  u += 0x7fffu + ((u>>16)&1u);
  return (unsigned short)(u>>16);
}
__device__ __forceinline__ float bf2f(unsigned short h){
  unsigned u = ((unsigned)h)<<16;
  return __builtin_bit_cast(float, u);
}
__device__ __forceinline__ void gload_lds16(const unsigned short* g, unsigned short* l){
  __builtin_amdgcn_global_load_lds((const __attribute__((address_space(1))) void*)g,
                                   (__attribute__((address_space(3))) void*)l,
                                   16, 0, 0);
}

// ---------------- cast fp32 -> bf16 (query, in_proj_w, out_proj_w) ----------------
__global__ __launch_bounds__(256) void cast_all(
    const float* __restrict__ q, const float* __restrict__ wi, const float* __restrict__ wo,
    unsigned short* __restrict__ qq, unsigned short* __restrict__ wib, unsigned short* __restrict__ wob)
{
  int i4 = (blockIdx.x*256 + threadIdx.x)*4;
  const float* src; unsigned short* dst; int off;
  if (i4 < 4194304)       { src=q;  dst=qq;  off=i4; }
  else if (i4 < 7340032)  { src=wi; dst=wib; off=i4-4194304; }
  else                    { src=wo; dst=wob; off=i4-7340032; }
  float4 v = *(const float4*)(src+off);
  us4 o; o.x=f2bf(v.x); o.y=f2bf(v.y); o.z=f2bf(v.z); o.w=f2bf(v.w);
  *(us4*)(dst+off) = o;
}

// ---------------- GEMM-BT 128x128, BK=64: qkv = query @ W_in^T + b -----------------
// 2D-chunked XCD placement (R15-verified).
__global__ __launch_bounds__(256) void gemm_qkv(
    const unsigned short* __restrict__ A, const unsigned short* __restrict__ Bw,
    const float* __restrict__ bias,
    unsigned short* __restrict__ qo, unsigned short* __restrict__ ko, unsigned short* __restrict__ vTo)
{
  __shared__ unsigned short lA[128*64];
  __shared__ unsigned short lB[128*64];
  int tid = threadIdx.x, lane = tid&63, w = tid>>6;
  int wr = (w>>1)<<6, wc = (w&1)<<6;
  int lin = blockIdx.y*24 + blockIdx.x;
  int xcd = lin & 7, idx = lin >> 3;          // 96 blocks per XCD
  int rg = xcd >> 1, cg = xcd & 1;
  int rowT = ((rg<<3) + (idx & 7)) << 7;      // row tile 0..31
  int colT = (cg*12 + (idx >> 3)) << 7;       // col tile 0..23
  f32x4 acc[4][4] = {};
  for (int k0=0; k0<1024; k0+=64){
    #pragma unroll
    for (int it=0; it<4; ++it){
      int ci = it*256+tid; int r=ci>>3, cs=ci&7;
      int c = (cs ^ (r&7))<<3;
      gload_lds16(A + (size_t)(rowT+r)*1024 + k0 + c, &lA[ci<<3]);
    }
    #pragma unroll
    for (int it=0; it<4; ++it){
      int ci = it*256+tid; int r=ci>>3, cs=ci&7;
      int c = (cs ^ (r&7))<<3;
      gload_lds16(Bw + (size_t)(colT+r)*1024 + k0 + c, &lB[ci<<3]);
    }
    asm volatile("s_waitcnt vmcnt(0)" ::: "memory");
    __syncthreads();
    #pragma unroll
    for (int kk=0; kk<2; ++kk){
      int kc = (kk<<2) + (lane>>4);
      bf16x8 a[4], b[4];
      #pragma unroll
      for (int i=0;i<4;++i){
        int r = wr + (i<<4) + (lane&15);
        a[i] = *(const bf16x8*)&lA[(r<<6) + ((kc ^ (r&7))<<3)];
      }
      #pragma unroll
      for (int j=0;j<4;++j){
        int r = wc + (j<<4) + (lane&15);
        b[j] = *(const bf16x8*)&lB[(r<<6) + ((kc ^ (r&7))<<3)];
      }
      #pragma unroll
      for (int i=0;i<4;++i)
        #pragma unroll
        for (int j=0;j<4;++j)
          acc[i][j] = MFMA16(a[i], b[j], acc[i][j]);
    }
    __syncthreads();
  }
  int sec = colT >> 10;
  #pragma unroll
  for (int i=0;i<4;++i){
    #pragma unroll
    for (int j=0;j<4;++j){
      int cg2 = colT + wc + (j<<4) + (lane&15);
      int d = cg2 & 1023, hh = d>>6, di = d&63;
      float bsv = bias[cg2];
      #pragma unroll
      for (int q=0;q<4;++q){
        int m = rowT + wr + (i<<4) + ((lane>>4)<<2) + q;
        int b = m>>10, n = m&1023;
        unsigned short bv = f2bf(acc[i][j][q] + bsv);
        size_t bh = (size_t)((b<<4) + hh);
        if (sec==0)      qo[(bh<<16) + ((size_t)n<<6) + di] = bv;
        else if (sec==1) ko[(bh<<16) + ((size_t)n<<6) + di] = bv;
        else             vTo[(bh<<16) + ((size_t)di<<10) + n] = bv;
      }
    }
  }
}

// ---------------- GEMM-BT 128x128: out = oa @ W_out^T + b (fp32 out) ----------------
// 2D-chunked XCD placement (R15-verified); normal cached stores (nt regressed, R16).
__global__ __launch_bounds__(256) void gemm_out(
    const unsigned short* __restrict__ A, const unsigned short* __restrict__ Bw,
    const float* __restrict__ bias, float* __restrict__ out)
{
  __shared__ unsigned short lA[128*64];
  __shared__ unsigned short lB[128*64];
  int tid = threadIdx.x, lane = tid&63, w = tid>>6;
  int wr = (w>>1)<<6, wc = (w&1)<<6;
  int lin = blockIdx.y*8 + blockIdx.x;
  int xcd = lin & 7, idx = lin >> 3;          // 32 blocks per XCD
  int rg = xcd >> 1, cg = xcd & 1;
  int rowT = ((rg<<3) + (idx & 7)) << 7;      // row tile 0..31
  int colT = ((cg<<2) + (idx >> 3)) << 7;     // col tile 0..7
  f32x4 acc[4][4] = {};
  for (int k0=0; k0<1024; k0+=64){
    #pragma unroll
    for (int it=0; it<4; ++it){
      int ci = it*256+tid; int r=ci>>3, cs=ci&7;
      int c = (cs ^ (r&7))<<3;
      gload_lds16(A + (size_t)(rowT+r)*1024 + k0 + c, &lA[ci<<3]);
    }
    #pragma unroll
    for (int it=0; it<4; ++it){
      int ci = it*256+tid; int r=ci>>3, cs=ci&7;
      int c = (cs ^ (r&7))<<3;
      gload_lds16(Bw + (size_t)(colT+r)*1024 + k0 + c, &lB[ci<<3]);
    }
    asm volatile("s_waitcnt vmcnt(0)" ::: "memory");
    __syncthreads();
    #pragma unroll
    for (int kk=0; kk<2; ++kk){
      int kc = (kk<<2) + (lane>>4);
      bf16x8 a[4], b[4];
      #pragma unroll
      for (int i=0;i<4;++i){
        int r = wr + (i<<4) + (lane&15);
        a[i] = *(const bf16x8*)&lA[(r<<6) + ((kc ^ (r&7))<<3)];
      }
      #pragma unroll
      for (int j=0;j<4;++j){
        int r = wc + (j<<4) + (lane&15);
        b[j] = *(const bf16x8*)&lB[(r<<6) + ((kc ^ (r&7))<<3)];
      }
      #pragma unroll
      for (int i=0;i<4;++i)
        #pragma unroll
        for (int j=0;j<4;++j)
          acc[i][j] = MFMA16(a[i], b[j], acc[i][j]);
    }
    __syncthreads();
  }
  #pragma unroll
  for (int i=0;i<4;++i){
    #pragma unroll
    for (int j=0;j<4;++j){
      int cg2 = colT + wc + (j<<4) + (lane&15);
      float bsv = bias[cg2];
      #pragma unroll
      for (int q=0;q<4;++q){
        int m = rowT + wr + (i<<4) + ((lane>>4)<<2) + q;
        out[(size_t)m*1024 + cg2] = acc[i][j][q] + bsv;
      }
    }
  }
}

// ---------------- fused attention: one WG = one (b,h) x 32-row stripe ----------------
// R15 version + s_setprio(1) around MFMA clusters (T5: wave role diversity from the
// C||D interleave + 2 staggered blocks/CU makes priority arbitration meaningful).
__global__ __launch_bounds__(256) void attn_fused(
    const unsigned short* __restrict__ qbf, const unsigned short* __restrict__ kbf,
    const unsigned short* __restrict__ vT, const float* __restrict__ tbl,
    float* __restrict__ attn_out, unsigned short* __restrict__ oa)
{
  __shared__ unsigned short P[32*1024];   // 64 KB, XOR-swizzled 16B chunks
  __shared__ unsigned short qs[32*64];    // 4 KB, swizzled
  __shared__ float biasv[64];
  __shared__ float rsum[4][32];
  __shared__ float rinv_s[32];

  int tid=threadIdx.x, lane=tid&63, w=tid>>6;
  int bid = blockIdx.x;
  int wgid = ((bid&7)<<8) + (bid>>3);     // XCD swizzle: 8 pairs per XCD -> K/V L2-resident
  int pair = wgid >> 5;                   // b*16 + h
  int stripe = wgid & 31;
  int h = pair & 15;
  int bg = pair >> 4;
  int nbase = stripe<<5;
  const unsigned short* qg = qbf + ((size_t)pair<<16) + ((size_t)nbase<<6);
  const unsigned short* kg = kbf + ((size_t)pair<<16);
  const unsigned short* vg = vT  + ((size_t)pair<<16);

  // per-head bias LUT over relative offset d in [-31,31]
  if (tid < 63){
    int dd = tid - 31;
    int neg = dd<0 ? 1:0;
    int a = dd<0 ? -dd : dd;
    int bkt;
    if (a<16) bkt = a;
    else bkt = 16 + (int)(__logf((float)a*(1.f/16.f)) * (16.f/__logf(8.f)));
    bkt += neg*32;
    biasv[tid] = tbl[(bkt<<4) + h];
  }
  // stage q stripe 32x64 (swizzled)
  { int r=tid>>3, cs=tid&7;
    int c = (cs ^ (r&7))<<3;
    gload_lds16(qg + (r<<6) + c, &qs[tid<<3]); }
  asm volatile("s_waitcnt vmcnt(0)" ::: "memory");
  __syncthreads();

  int x = lane&15, g = lane>>4;
  // col-term bias: 12 registers, loaded once (static indices -> stays in VGPRs)
  float cterm[3][4];
  #pragma unroll
  for (int s=0;s<3;++s)
    #pragma unroll
    for (int q=0;q<4;++q)
      cterm[s][q] = biasv[(g<<2) + q - x + 31 + ((s-1)<<4)];

  // hoisted Q fragments: invariant across the whole column loop
  bf16x8 qa[2][2];
  #pragma unroll
  for (int rt=0;rt<2;++rt){
    int r = (rt<<4) + x;
    #pragma unroll
    for (int hh=0;hh<2;++hh)
      qa[rt][hh] = *(const bf16x8*)&qs[(r<<6) + ((((hh<<2)+g) ^ (r&7))<<3)];
  }

  // phase B: logits -> exp -> P(bf16), per-wave 256-col slice
  float rs[2][4] = {};
  int colW = w<<8;
  for (int ct2=0; ct2<8; ++ct2){
    int cbb = colW + (ct2<<5);
    float rterm = biasv[stripe - (cbb>>5) + 31];   // wave-uniform row term
    #pragma unroll
    for (int par=0; par<2; ++par){
      int cb = cbb + (par<<4);
      int j = cb + x;
      const unsigned short* kp = kg + ((size_t)j<<6) + (g<<3);
      bf16x8 bk0 = *(const bf16x8*)kp;
      bf16x8 bk1 = *(const bf16x8*)(kp+32);
      #pragma unroll
      for (int rt=0; rt<2; ++rt){
        f32x4 acc = {};
        __builtin_amdgcn_s_setprio(1);
        acc = MFMA16(qa[rt][0], bk0, acc);
        acc = MFMA16(qa[rt][1], bk1, acc);
        __builtin_amdgcn_s_setprio(0);
        #pragma unroll
        for (int q=0;q<4;++q){
          int r = (rt<<4) + (g<<2) + q;
          float lg = acc[q]*0.125f + rterm + cterm[rt+1-par][q];
          float e = __expf(lg);
          rs[rt][q] += e;
          int byteoff = (r<<11) + ((((j>>3) ^ (r&7)))<<4) + ((j&7)<<1);
          *(unsigned short*)((char*)P + byteoff) = f2bf(e);
        }
      }
    }
  }
  // row sums: butterfly over 16 col-lanes, then cross-wave via LDS
  #pragma unroll
  for (int rt=0;rt<2;++rt){
    #pragma unroll
    for (int q=0;q<4;++q){
      float v = rs[rt][q];
      v += __shfl_xor(v,1); v += __shfl_xor(v,2); v += __shfl_xor(v,4); v += __shfl_xor(v,8);
      if (x==0) rsum[w][(rt<<4)+(g<<2)+q] = v;
    }
  }
  __syncthreads();
  if (tid<32) rinv_s[tid] = 1.f/(rsum[0][tid]+rsum[1][tid]+rsum[2][tid]+rsum[3][tid]);
  __syncthreads();

  // phases C+D interleaved over 8 column-blocks of 128
  float* ao = attn_out + ((size_t)pair<<20) + ((size_t)nbase<<10);
  f32x4 oacc[2] = {};
  int dbase = w<<4;
  const unsigned short* vp = vg + ((size_t)(dbase + x)<<10) + (g<<3);
  for (int cbk=0; cbk<8; ++cbk){
    // C slice: 32 rows x 128 cols
    #pragma unroll
    for (int it=0; it<2; ++it){
      int r = (it<<4) + (tid>>4);
      int c8 = (cbk<<7) + ((tid&15)<<3);
      int byteoff = (r<<11) + ((((c8>>3) ^ (r&7)))<<4);
      bf16x8 pv8 = *(const bf16x8*)((char*)P + byteoff);
      float ri = rinv_s[r];
      float4 o0, o1;
      o0.x = bf2f((unsigned short)pv8[0])*ri;
      o0.y = bf2f((unsigned short)pv8[1])*ri;
      o0.z = bf2f((unsigned short)pv8[2])*ri;
      o0.w = bf2f((unsigned short)pv8[3])*ri;
      o1.x = bf2f((unsigned short)pv8[4])*ri;
      o1.y = bf2f((unsigned short)pv8[5])*ri;
      o1.z = bf2f((unsigned short)pv8[6])*ri;
      o1.w = bf2f((unsigned short)pv8[7])*ri;
      *(float4*)(ao + ((size_t)r<<10) + c8)     = o0;
      *(float4*)(ao + ((size_t)r<<10) + c8 + 4) = o1;
    }
    // D slice: 128 K-steps of PV (priority-boosted MFMA cluster)
    __builtin_amdgcn_s_setprio(1);
    #pragma unroll
    for (int ks=0; ks<4; ++ks){
      int kc = (cbk<<7) + (ks<<5);
      bf16x8 bv = *(const bf16x8*)(vp + kc);
      int ck = (kc>>3) + g;
      #pragma unroll
      for (int rt=0;rt<2;++rt){
        int r = (rt<<4) + x;
        bf16x8 a = *(const bf16x8*)((char*)P + (r<<11) + ((ck ^ (r&7))<<4));
        oacc[rt] = MFMA16(a, bv, oacc[rt]);
      }
    }
    __builtin_amdgcn_s_setprio(0);
  }
  #pragma unroll
  for (int rt=0;rt<2;++rt){
    #pragma unroll
    for (int q=0;q<4;++q){
      int r = (rt<<4) + (g<<2) + q;
      float val = oacc[rt][q]*rinv_s[r];
      oa[((size_t)((bg<<10) + nbase + r)<<10) + (h<<6) + dbase + x] = f2bf(val);
    }
  }
}

extern "C" void kernel_launch(void* const* d_in, const int* in_sizes, int n_in,
                              void* d_out, int out_size, void* d_ws, size_t ws_size,
                              hipStream_t stream)
{
  const float* query = (const float*)d_in[0];
  const float* wi  = (const float*)d_in[3];
  const float* bi  = (const float*)d_in[4];
  const float* wo  = (const float*)d_in[5];
  const float* bo  = (const float*)d_in[6];
  const float* tbl = (const float*)d_in[7];

  char* ws = (char*)d_ws;
  unsigned short* qq  = (unsigned short*)(ws);              // query bf16   8 MB
  unsigned short* wib = (unsigned short*)(ws + 8388608);    // W_in bf16    6 MB
  unsigned short* wob = (unsigned short*)(ws + 14680064);   // W_out bf16   2 MB
  unsigned short* qbf = (unsigned short*)(ws + 16777216);   // q [B,H,N,hd] 8 MB
  unsigned short* kbf = (unsigned short*)(ws + 25165824);   // k [B,H,N,hd] 8 MB
  unsigned short* vTb = (unsigned short*)(ws + 33554432);   // vT [B,H,hd,N] 8 MB
  unsigned short* oa  = (unsigned short*)(ws + 41943040);   // out_attn bf16 8 MB

  float* out  = (float*)d_out;
  float* attn = out + 4194304;

  cast_all<<<dim3(8192), dim3(256), 0, stream>>>(query, wi, wo, qq, wib, wob);
  gemm_qkv<<<dim3(24,32), dim3(256), 0, stream>>>(qq, wib, bi, qbf, kbf, vTb);
  attn_fused<<<dim3(2048), dim3(256), 0, stream>>>(qbf, kbf, vTb, tbl, attn, oa);
  gemm_out<<<dim3(8,32), dim3(256), 0, stream>>>(oa, wob, bo, out);
}

// Round 18
// 177.123 us; speedup vs baseline: 1.2493x; 1.0617x over previous
//
#include <hip/hip_runtime.h>
#include <hip/hip_bf16.h>

typedef __attribute__((ext_vector_type(8))) short bf16x8;
typedef __attribute__((ext_vector_type(4))) float f32x4;
typedef __attribute__((ext_vector_type(4))) unsigned short us4;

#define MFMA16(a,b,c) __builtin_amdgcn_mfma_f32_16x16x32_bf16((a),(b),(c),0,0,0)

__device__ __forceinline__ unsigned short f2bf(float f){
  unsigned u = __builtin_bit_cast(unsigned, f);
  u += 0x7fffu + ((u>>16)&1u);
  return (unsigned short)(u>>16);
}
__device__ __forceinline__ float bf2f(unsigned short h){
  unsigned u = ((unsigned)h)<<16;
  return __builtin_bit_cast(float, u);
}
__device__ __forceinline__ void gload_lds16(const unsigned short* g, unsigned short* l){
  __builtin_amdgcn_global_load_lds((const __attribute__((address_space(1))) void*)g,
                                   (__attribute__((address_space(3))) void*)l,
                                   16, 0, 0);
}

// ---------------- cast fp32 -> bf16 (query, in_proj_w, out_proj_w) ----------------
__global__ __launch_bounds__(256) void cast_all(
    const float* __restrict__ q, const float* __restrict__ wi, const float* __restrict__ wo,
    unsigned short* __restrict__ qq, unsigned short* __restrict__ wib, unsigned short* __restrict__ wob)
{
  int i4 = (blockIdx.x*256 + threadIdx.x)*4;
  const float* src; unsigned short* dst; int off;
  if (i4 < 4194304)       { src=q;  dst=qq;  off=i4; }
  else if (i4 < 7340032)  { src=wi; dst=wib; off=i4-4194304; }
  else                    { src=wo; dst=wob; off=i4-7340032; }
  float4 v = *(const float4*)(src+off);
  us4 o; o.x=f2bf(v.x); o.y=f2bf(v.y); o.z=f2bf(v.z); o.w=f2bf(v.w);
  *(us4*)(dst+off) = o;
}

// ---------------- GEMM-BT 128x128, BK=64: qkv = query @ W_in^T + b -----------------
// 2D-chunked XCD placement (R15-verified).
__global__ __launch_bounds__(256) void gemm_qkv(
    const unsigned short* __restrict__ A, const unsigned short* __restrict__ Bw,
    const float* __restrict__ bias,
    unsigned short* __restrict__ qo, unsigned short* __restrict__ ko, unsigned short* __restrict__ vTo)
{
  __shared__ unsigned short lA[128*64];
  __shared__ unsigned short lB[128*64];
  int tid = threadIdx.x, lane = tid&63, w = tid>>6;
  int wr = (w>>1)<<6, wc = (w&1)<<6;
  int lin = blockIdx.y*24 + blockIdx.x;
  int xcd = lin & 7, idx = lin >> 3;          // 96 blocks per XCD
  int rg = xcd >> 1, cg = xcd & 1;
  int rowT = ((rg<<3) + (idx & 7)) << 7;      // row tile 0..31
  int colT = (cg*12 + (idx >> 3)) << 7;       // col tile 0..23
  f32x4 acc[4][4] = {};
  for (int k0=0; k0<1024; k0+=64){
    #pragma unroll
    for (int it=0; it<4; ++it){
      int ci = it*256+tid; int r=ci>>3, cs=ci&7;
      int c = (cs ^ (r&7))<<3;
      gload_lds16(A + (size_t)(rowT+r)*1024 + k0 + c, &lA[ci<<3]);
    }
    #pragma unroll
    for (int it=0; it<4; ++it){
      int ci = it*256+tid; int r=ci>>3, cs=ci&7;
      int c = (cs ^ (r&7))<<3;
      gload_lds16(Bw + (size_t)(colT+r)*1024 + k0 + c, &lB[ci<<3]);
    }
    asm volatile("s_waitcnt vmcnt(0)" ::: "memory");
    __syncthreads();
    #pragma unroll
    for (int kk=0; kk<2; ++kk){
      int kc = (kk<<2) + (lane>>4);
      bf16x8 a[4], b[4];
      #pragma unroll
      for (int i=0;i<4;++i){
        int r = wr + (i<<4) + (lane&15);
        a[i] = *(const bf16x8*)&lA[(r<<6) + ((kc ^ (r&7))<<3)];
      }
      #pragma unroll
      for (int j=0;j<4;++j){
        int r = wc + (j<<4) + (lane&15);
        b[j] = *(const bf16x8*)&lB[(r<<6) + ((kc ^ (r&7))<<3)];
      }
      #pragma unroll
      for (int i=0;i<4;++i)
        #pragma unroll
        for (int j=0;j<4;++j)
          acc[i][j] = MFMA16(a[i], b[j], acc[i][j]);
    }
    __syncthreads();
  }
  int sec = colT >> 10;
  #pragma unroll
  for (int i=0;i<4;++i){
    #pragma unroll
    for (int j=0;j<4;++j){
      int cg2 = colT + wc + (j<<4) + (lane&15);
      int d = cg2 & 1023, hh = d>>6, di = d&63;
      float bsv = bias[cg2];
      #pragma unroll
      for (int q=0;q<4;++q){
        int m = rowT + wr + (i<<4) + ((lane>>4)<<2) + q;
        int b = m>>10, n = m&1023;
        unsigned short bv = f2bf(acc[i][j][q] + bsv);
        size_t bh = (size_t)((b<<4) + hh);
        if (sec==0)      qo[(bh<<16) + ((size_t)n<<6) + di] = bv;
        else if (sec==1) ko[(bh<<16) + ((size_t)n<<6) + di] = bv;
        else             vTo[(bh<<16) + ((size_t)di<<10) + n] = bv;
      }
    }
  }
}

// ---------------- GEMM-BT 128x128: out = oa @ W_out^T + b (fp32 out) ----------------
// 2D-chunked XCD placement (R15-verified).
__global__ __launch_bounds__(256) void gemm_out(
    const unsigned short* __restrict__ A, const unsigned short* __restrict__ Bw,
    const float* __restrict__ bias, float* __restrict__ out)
{
  __shared__ unsigned short lA[128*64];
  __shared__ unsigned short lB[128*64];
  int tid = threadIdx.x, lane = tid&63, w = tid>>6;
  int wr = (w>>1)<<6, wc = (w&1)<<6;
  int lin = blockIdx.y*8 + blockIdx.x;
  int xcd = lin & 7, idx = lin >> 3;          // 32 blocks per XCD
  int rg = xcd >> 1, cg = xcd & 1;
  int rowT = ((rg<<3) + (idx & 7)) << 7;      // row tile 0..31
  int colT = ((cg<<2) + (idx >> 3)) << 7;     // col tile 0..7
  f32x4 acc[4][4] = {};
  for (int k0=0; k0<1024; k0+=64){
    #pragma unroll
    for (int it=0; it<4; ++it){
      int ci = it*256+tid; int r=ci>>3, cs=ci&7;
      int c = (cs ^ (r&7))<<3;
      gload_lds16(A + (size_t)(rowT+r)*1024 + k0 + c, &lA[ci<<3]);
    }
    #pragma unroll
    for (int it=0; it<4; ++it){
      int ci = it*256+tid; int r=ci>>3, cs=ci&7;
      int c = (cs ^ (r&7))<<3;
      gload_lds16(Bw + (size_t)(colT+r)*1024 + k0 + c, &lB[ci<<3]);
    }
    asm volatile("s_waitcnt vmcnt(0)" ::: "memory");
    __syncthreads();
    #pragma unroll
    for (int kk=0; kk<2; ++kk){
      int kc = (kk<<2) + (lane>>4);
      bf16x8 a[4], b[4];
      #pragma unroll
      for (int i=0;i<4;++i){
        int r = wr + (i<<4) + (lane&15);
        a[i] = *(const bf16x8*)&lA[(r<<6) + ((kc ^ (r&7))<<3)];
      }
      #pragma unroll
      for (int j=0;j<4;++j){
        int r = wc + (j<<4) + (lane&15);
        b[j] = *(const bf16x8*)&lB[(r<<6) + ((kc ^ (r&7))<<3)];
      }
      #pragma unroll
      for (int i=0;i<4;++i)
        #pragma unroll
        for (int j=0;j<4;++j)
          acc[i][j] = MFMA16(a[i], b[j], acc[i][j]);
    }
    __syncthreads();
  }
  #pragma unroll
  for (int i=0;i<4;++i){
    #pragma unroll
    for (int j=0;j<4;++j){
      int cg2 = colT + wc + (j<<4) + (lane&15);
      float bsv = bias[cg2];
      #pragma unroll
      for (int q=0;q<4;++q){
        int m = rowT + wr + (i<<4) + ((lane>>4)<<2) + q;
        out[(size_t)m*1024 + cg2] = acc[i][j][q] + bsv;
      }
    }
  }
}

// ---------------- fused attention: one WG = one (b,h) x 32-row stripe ----------------
// R15 base (C+D interleave, XCD swizzle) + isolated 2-deep K register prefetch in
// phase B (R5's refcheck'd loop; R5's regression is now attributed to nt-stores).
__global__ __launch_bounds__(256) void attn_fused(
    const unsigned short* __restrict__ qbf, const unsigned short* __restrict__ kbf,
    const unsigned short* __restrict__ vT, const float* __restrict__ tbl,
    float* __restrict__ attn_out, unsigned short* __restrict__ oa)
{
  __shared__ unsigned short P[32*1024];   // 64 KB, XOR-swizzled 16B chunks
  __shared__ unsigned short qs[32*64];    // 4 KB, swizzled
  __shared__ float biasv[64];
  __shared__ float rsum[4][32];
  __shared__ float rinv_s[32];

  int tid=threadIdx.x, lane=tid&63, w=tid>>6;
  int bid = blockIdx.x;
  int wgid = ((bid&7)<<8) + (bid>>3);     // XCD swizzle: 8 pairs per XCD -> K/V L2-resident
  int pair = wgid >> 5;                   // b*16 + h
  int stripe = wgid & 31;
  int h = pair & 15;
  int bg = pair >> 4;
  int nbase = stripe<<5;
  const unsigned short* qg = qbf + ((size_t)pair<<16) + ((size_t)nbase<<6);
  const unsigned short* kg = kbf + ((size_t)pair<<16);
  const unsigned short* vg = vT  + ((size_t)pair<<16);

  // per-head bias LUT over relative offset d in [-31,31]
  if (tid < 63){
    int dd = tid - 31;
    int neg = dd<0 ? 1:0;
    int a = dd<0 ? -dd : dd;
    int bkt;
    if (a<16) bkt = a;
    else bkt = 16 + (int)(__logf((float)a*(1.f/16.f)) * (16.f/__logf(8.f)));
    bkt += neg*32;
    biasv[tid] = tbl[(bkt<<4) + h];
  }
  // stage q stripe 32x64 (swizzled)
  { int r=tid>>3, cs=tid&7;
    int c = (cs ^ (r&7))<<3;
    gload_lds16(qg + (r<<6) + c, &qs[tid<<3]); }
  asm volatile("s_waitcnt vmcnt(0)" ::: "memory");
  __syncthreads();

  int x = lane&15, g = lane>>4;
  // col-term bias: 12 registers, loaded once (static indices -> stays in VGPRs)
  float cterm[3][4];
  #pragma unroll
  for (int s=0;s<3;++s)
    #pragma unroll
    for (int q=0;q<4;++q)
      cterm[s][q] = biasv[(g<<2) + q - x + 31 + ((s-1)<<4)];

  // hoisted Q fragments: invariant across the whole column loop
  bf16x8 qa[2][2];
  #pragma unroll
  for (int rt=0;rt<2;++rt){
    int r = (rt<<4) + x;
    #pragma unroll
    for (int hh=0;hh<2;++hh)
      qa[rt][hh] = *(const bf16x8*)&qs[(r<<6) + ((((hh<<2)+g) ^ (r&7))<<3)];
  }

  // phase B: logits -> exp -> P(bf16); flat col-tile loop, 2-deep K prefetch
  float rs[2][4] = {};
  int colW = w<<8;
  const unsigned short* kbase = kg + ((size_t)x<<6) + (g<<3);
  bf16x8 nb0 = *(const bf16x8*)(kbase + ((size_t)colW<<6));
  bf16x8 nb1 = *(const bf16x8*)(kbase + ((size_t)colW<<6) + 32);
  #pragma unroll 2
  for (int t=0; t<16; ++t){
    bf16x8 bk0 = nb0, bk1 = nb1;
    if (t < 15){
      const unsigned short* kp = kbase + ((size_t)(colW + ((t+1)<<4))<<6);
      nb0 = *(const bf16x8*)kp;
      nb1 = *(const bf16x8*)(kp+32);
    }
    int cb = colW + (t<<4);
    int j = cb + x;
    int par = t&1;
    float rterm = biasv[stripe - (cb>>5) + 31];   // wave-uniform row term
    #pragma unroll
    for (int rt=0; rt<2; ++rt){
      f32x4 acc = {};
      acc = MFMA16(qa[rt][0], bk0, acc);
      acc = MFMA16(qa[rt][1], bk1, acc);
      #pragma unroll
      for (int q=0;q<4;++q){
        int r = (rt<<4) + (g<<2) + q;
        float lg = acc[q]*0.125f + rterm + cterm[rt+1-par][q];
        float e = __expf(lg);
        rs[rt][q] += e;
        int byteoff = (r<<11) + ((((j>>3) ^ (r&7)))<<4) + ((j&7)<<1);
        *(unsigned short*)((char*)P + byteoff) = f2bf(e);
      }
    }
  }
  // row sums: butterfly over 16 col-lanes, then cross-wave via LDS
  #pragma unroll
  for (int rt=0;rt<2;++rt){
    #pragma unroll
    for (int q=0;q<4;++q){
      float v = rs[rt][q];
      v += __shfl_xor(v,1); v += __shfl_xor(v,2); v += __shfl_xor(v,4); v += __shfl_xor(v,8);
      if (x==0) rsum[w][(rt<<4)+(g<<2)+q] = v;
    }
  }
  __syncthreads();
  if (tid<32) rinv_s[tid] = 1.f/(rsum[0][tid]+rsum[1][tid]+rsum[2][tid]+rsum[3][tid]);
  __syncthreads();

  // phases C+D interleaved over 8 column-blocks of 128
  float* ao = attn_out + ((size_t)pair<<20) + ((size_t)nbase<<10);
  f32x4 oacc[2] = {};
  int dbase = w<<4;
  const unsigned short* vp = vg + ((size_t)(dbase + x)<<10) + (g<<3);
  for (int cbk=0; cbk<8; ++cbk){
    // C slice: 32 rows x 128 cols
    #pragma unroll
    for (int it=0; it<2; ++it){
      int r = (it<<4) + (tid>>4);
      int c8 = (cbk<<7) + ((tid&15)<<3);
      int byteoff = (r<<11) + ((((c8>>3) ^ (r&7)))<<4);
      bf16x8 pv8 = *(const bf16x8*)((char*)P + byteoff);
      float ri = rinv_s[r];
      float4 o0, o1;
      o0.x = bf2f((unsigned short)pv8[0])*ri;
      o0.y = bf2f((unsigned short)pv8[1])*ri;
      o0.z = bf2f((unsigned short)pv8[2])*ri;
      o0.w = bf2f((unsigned short)pv8[3])*ri;
      o1.x = bf2f((unsigned short)pv8[4])*ri;
      o1.y = bf2f((unsigned short)pv8[5])*ri;
      o1.z = bf2f((unsigned short)pv8[6])*ri;
      o1.w = bf2f((unsigned short)pv8[7])*ri;
      *(float4*)(ao + ((size_t)r<<10) + c8)     = o0;
      *(float4*)(ao + ((size_t)r<<10) + c8 + 4) = o1;
    }
    // D slice: 128 K-steps of PV
    #pragma unroll
    for (int ks=0; ks<4; ++ks){
      int kc = (cbk<<7) + (ks<<5);
      bf16x8 bv = *(const bf16x8*)(vp + kc);
      int ck = (kc>>3) + g;
      #pragma unroll
      for (int rt=0;rt<2;++rt){
        int r = (rt<<4) + x;
        bf16x8 a = *(const bf16x8*)((char*)P + (r<<11) + ((ck ^ (r&7))<<4));
        oacc[rt] = MFMA16(a, bv, oacc[rt]);
      }
    }
  }
  #pragma unroll
  for (int rt=0;rt<2;++rt){
    #pragma unroll
    for (int q=0;q<4;++q){
      int r = (rt<<4) + (g<<2) + q;
      float val = oacc[rt][q]*rinv_s[r];
      oa[((size_t)((bg<<10) + nbase + r)<<10) + (h<<6) + dbase + x] = f2bf(val);
    }
  }
}

extern "C" void kernel_launch(void* const* d_in, const int* in_sizes, int n_in,
                              void* d_out, int out_size, void* d_ws, size_t ws_size,
                              hipStream_t stream)
{
  const float* query = (const float*)d_in[0];
  const float* wi  = (const float*)d_in[3];
  const float* bi  = (const float*)d_in[4];
  const float* wo  = (const float*)d_in[5];
  const float* bo  = (const float*)d_in[6];
  const float* tbl = (const float*)d_in[7];

  char* ws = (char*)d_ws;
  unsigned short* qq  = (unsigned short*)(ws);              // query bf16   8 MB
  unsigned short* wib = (unsigned short*)(ws + 8388608);    // W_in bf16    6 MB
  unsigned short* wob = (unsigned short*)(ws + 14680064);   // W_out bf16   2 MB
  unsigned short* qbf = (unsigned short*)(ws + 16777216);   // q [B,H,N,hd] 8 MB
  unsigned short* kbf = (unsigned short*)(ws + 25165824);   // k [B,H,N,hd] 8 MB
  unsigned short* vTb = (unsigned short*)(ws + 33554432);   // vT [B,H,hd,N] 8 MB
  unsigned short* oa  = (unsigned short*)(ws + 41943040);   // out_attn bf16 8 MB

  float* out  = (float*)d_out;
  float* attn = out + 4194304;

  cast_all<<<dim3(8192), dim3(256), 0, stream>>>(query, wi, wo, qq, wib, wob);
  gemm_qkv<<<dim3(24,32), dim3(256), 0, stream>>>(qq, wib, bi, qbf, kbf, vTb);
  attn_fused<<<dim3(2048), dim3(256), 0, stream>>>(qbf, kbf, vTb, tbl, attn, oa);
  gemm_out<<<dim3(8,32), dim3(256), 0, stream>>>(oa, wob, bo, out);
}

// Round 19
// 176.162 us; speedup vs baseline: 1.2561x; 1.0055x over previous
//
#include <hip/hip_runtime.h>
#include <hip/hip_bf16.h>

typedef __attribute__((ext_vector_type(8))) short bf16x8;
typedef __attribute__((ext_vector_type(4))) float f32x4;
typedef __attribute__((ext_vector_type(4))) unsigned short us4;

#define MFMA16(a,b,c) __builtin_amdgcn_mfma_f32_16x16x32_bf16((a),(b),(c),0,0,0)

__device__ __forceinline__ unsigned short f2bf(float f){
  unsigned u = __builtin_bit_cast(unsigned, f);
  u += 0x7fffu + ((u>>16)&1u);
  return (unsigned short)(u>>16);
}
__device__ __forceinline__ float bf2f(unsigned short h){
  unsigned u = ((unsigned)h)<<16;
  return __builtin_bit_cast(float, u);
}
__device__ __forceinline__ void gload_lds16(const unsigned short* g, unsigned short* l){
  __builtin_amdgcn_global_load_lds((const __attribute__((address_space(1))) void*)g,
                                   (__attribute__((address_space(3))) void*)l,
                                   16, 0, 0);
}

// ---------------- cast fp32 -> bf16 (query, in_proj_w, out_proj_w) ----------------
__global__ __launch_bounds__(256) void cast_all(
    const float* __restrict__ q, const float* __restrict__ wi, const float* __restrict__ wo,
    unsigned short* __restrict__ qq, unsigned short* __restrict__ wib, unsigned short* __restrict__ wob)
{
  int i4 = (blockIdx.x*256 + threadIdx.x)*4;
  const float* src; unsigned short* dst; int off;
  if (i4 < 4194304)       { src=q;  dst=qq;  off=i4; }
  else if (i4 < 7340032)  { src=wi; dst=wib; off=i4-4194304; }
  else                    { src=wo; dst=wob; off=i4-7340032; }
  float4 v = *(const float4*)(src+off);
  us4 o; o.x=f2bf(v.x); o.y=f2bf(v.y); o.z=f2bf(v.z); o.w=f2bf(v.w);
  *(us4*)(dst+off) = o;
}

// ---------------- GEMM-BT 128x128, BK=64: qkv = query @ W_in^T + b -----------------
// 2D-chunked XCD placement (R15-verified).
__global__ __launch_bounds__(256) void gemm_qkv(
    const unsigned short* __restrict__ A, const unsigned short* __restrict__ Bw,
    const float* __restrict__ bias,
    unsigned short* __restrict__ qo, unsigned short* __restrict__ ko, unsigned short* __restrict__ vTo)
{
  __shared__ unsigned short lA[128*64];
  __shared__ unsigned short lB[128*64];
  int tid = threadIdx.x, lane = tid&63, w = tid>>6;
  int wr = (w>>1)<<6, wc = (w&1)<<6;
  int lin = blockIdx.y*24 + blockIdx.x;
  int xcd = lin & 7, idx = lin >> 3;          // 96 blocks per XCD
  int rg = xcd >> 1, cg = xcd & 1;
  int rowT = ((rg<<3) + (idx & 7)) << 7;      // row tile 0..31
  int colT = (cg*12 + (idx >> 3)) << 7;       // col tile 0..23
  f32x4 acc[4][4] = {};
  for (int k0=0; k0<1024; k0+=64){
    #pragma unroll
    for (int it=0; it<4; ++it){
      int ci = it*256+tid; int r=ci>>3, cs=ci&7;
      int c = (cs ^ (r&7))<<3;
      gload_lds16(A + (size_t)(rowT+r)*1024 + k0 + c, &lA[ci<<3]);
    }
    #pragma unroll
    for (int it=0; it<4; ++it){
      int ci = it*256+tid; int r=ci>>3, cs=ci&7;
      int c = (cs ^ (r&7))<<3;
      gload_lds16(Bw + (size_t)(colT+r)*1024 + k0 + c, &lB[ci<<3]);
    }
    asm volatile("s_waitcnt vmcnt(0)" ::: "memory");
    __syncthreads();
    #pragma unroll
    for (int kk=0; kk<2; ++kk){
      int kc = (kk<<2) + (lane>>4);
      bf16x8 a[4], b[4];
      #pragma unroll
      for (int i=0;i<4;++i){
        int r = wr + (i<<4) + (lane&15);
        a[i] = *(const bf16x8*)&lA[(r<<6) + ((kc ^ (r&7))<<3)];
      }
      #pragma unroll
      for (int j=0;j<4;++j){
        int r = wc + (j<<4) + (lane&15);
        b[j] = *(const bf16x8*)&lB[(r<<6) + ((kc ^ (r&7))<<3)];
      }
      #pragma unroll
      for (int i=0;i<4;++i)
        #pragma unroll
        for (int j=0;j<4;++j)
          acc[i][j] = MFMA16(a[i], b[j], acc[i][j]);
    }
    __syncthreads();
  }
  int sec = colT >> 10;
  #pragma unroll
  for (int i=0;i<4;++i){
    #pragma unroll
    for (int j=0;j<4;++j){
      int cg2 = colT + wc + (j<<4) + (lane&15);
      int d = cg2 & 1023, hh = d>>6, di = d&63;
      float bsv = bias[cg2];
      #pragma unroll
      for (int q=0;q<4;++q){
        int m = rowT + wr + (i<<4) + ((lane>>4)<<2) + q;
        int b = m>>10, n = m&1023;
        unsigned short bv = f2bf(acc[i][j][q] + bsv);
        size_t bh = (size_t)((b<<4) + hh);
        if (sec==0)      qo[(bh<<16) + ((size_t)n<<6) + di] = bv;
        else if (sec==1) ko[(bh<<16) + ((size_t)n<<6) + di] = bv;
        else             vTo[(bh<<16) + ((size_t)di<<10) + n] = bv;
      }
    }
  }
}

// ---------------- GEMM-BT 128x128: out = oa @ W_out^T + b (fp32 out) ----------------
// 2D-chunked XCD placement (R15-verified). This round: 512 threads / 8 waves per
// block (each wave 64x32 output) -> 2 waves/SIMD instead of 1; same tile, same LDS
// byte layout, same per-element MFMA order -> bit-identical results.
__global__ __launch_bounds__(512) void gemm_out(
    const unsigned short* __restrict__ A, const unsigned short* __restrict__ Bw,
    const float* __restrict__ bias, float* __restrict__ out)
{
  __shared__ unsigned short lA[128*64];
  __shared__ unsigned short lB[128*64];
  int tid = threadIdx.x, lane = tid&63, w = tid>>6;   // w 0..7
  int wr = (w>>2)<<6;        // 0 or 64
  int wc = (w&3)<<5;         // 0,32,64,96
  int lin = blockIdx.y*8 + blockIdx.x;
  int xcd = lin & 7, idx = lin >> 3;          // 32 blocks per XCD
  int rg = xcd >> 1, cg = xcd & 1;
  int rowT = ((rg<<3) + (idx & 7)) << 7;      // row tile 0..31
  int colT = ((cg<<2) + (idx >> 3)) << 7;     // col tile 0..7
  f32x4 acc[4][2] = {};
  for (int k0=0; k0<1024; k0+=64){
    #pragma unroll
    for (int it=0; it<2; ++it){
      int ci = it*512+tid; int r=ci>>3, cs=ci&7;
      int c = (cs ^ (r&7))<<3;
      gload_lds16(A + (size_t)(rowT+r)*1024 + k0 + c, &lA[ci<<3]);
      gload_lds16(Bw + (size_t)(colT+r)*1024 + k0 + c, &lB[ci<<3]);
    }
    asm volatile("s_waitcnt vmcnt(0)" ::: "memory");
    __syncthreads();
    #pragma unroll
    for (int kk=0; kk<2; ++kk){
      int kc = (kk<<2) + (lane>>4);
      bf16x8 a[4], b[2];
      #pragma unroll
      for (int i=0;i<4;++i){
        int r = wr + (i<<4) + (lane&15);
        a[i] = *(const bf16x8*)&lA[(r<<6) + ((kc ^ (r&7))<<3)];
      }
      #pragma unroll
      for (int j=0;j<2;++j){
        int r = wc + (j<<4) + (lane&15);
        b[j] = *(const bf16x8*)&lB[(r<<6) + ((kc ^ (r&7))<<3)];
      }
      #pragma unroll
      for (int i=0;i<4;++i)
        #pragma unroll
        for (int j=0;j<2;++j)
          acc[i][j] = MFMA16(a[i], b[j], acc[i][j]);
    }
    __syncthreads();
  }
  #pragma unroll
  for (int i=0;i<4;++i){
    #pragma unroll
    for (int j=0;j<2;++j){
      int cg2 = colT + wc + (j<<4) + (lane&15);
      float bsv = bias[cg2];
      #pragma unroll
      for (int q=0;q<4;++q){
        int m = rowT + wr + (i<<4) + ((lane>>4)<<2) + q;
        out[(size_t)m*1024 + cg2] = acc[i][j][q] + bsv;
      }
    }
  }
}

// ---------------- fused attention: one WG = one (b,h) x 32-row stripe ----------------
// R18 version (C+D interleave, XCD swizzle, 2-deep K prefetch), unchanged.
__global__ __launch_bounds__(256) void attn_fused(
    const unsigned short* __restrict__ qbf, const unsigned short* __restrict__ kbf,
    const unsigned short* __restrict__ vT, const float* __restrict__ tbl,
    float* __restrict__ attn_out, unsigned short* __restrict__ oa)
{
  __shared__ unsigned short P[32*1024];   // 64 KB, XOR-swizzled 16B chunks
  __shared__ unsigned short qs[32*64];    // 4 KB, swizzled
  __shared__ float biasv[64];
  __shared__ float rsum[4][32];
  __shared__ float rinv_s[32];

  int tid=threadIdx.x, lane=tid&63, w=tid>>6;
  int bid = blockIdx.x;
  int wgid = ((bid&7)<<8) + (bid>>3);     // XCD swizzle: 8 pairs per XCD -> K/V L2-resident
  int pair = wgid >> 5;                   // b*16 + h
  int stripe = wgid & 31;
  int h = pair & 15;
  int bg = pair >> 4;
  int nbase = stripe<<5;
  const unsigned short* qg = qbf + ((size_t)pair<<16) + ((size_t)nbase<<6);
  const unsigned short* kg = kbf + ((size_t)pair<<16);
  const unsigned short* vg = vT  + ((size_t)pair<<16);

  // per-head bias LUT over relative offset d in [-31,31]
  if (tid < 63){
    int dd = tid - 31;
    int neg = dd<0 ? 1:0;
    int a = dd<0 ? -dd : dd;
    int bkt;
    if (a<16) bkt = a;
    else bkt = 16 + (int)(__logf((float)a*(1.f/16.f)) * (16.f/__logf(8.f)));
    bkt += neg*32;
    biasv[tid] = tbl[(bkt<<4) + h];
  }
  // stage q stripe 32x64 (swizzled)
  { int r=tid>>3, cs=tid&7;
    int c = (cs ^ (r&7))<<3;
    gload_lds16(qg + (r<<6) + c, &qs[tid<<3]); }
  asm volatile("s_waitcnt vmcnt(0)" ::: "memory");
  __syncthreads();

  int x = lane&15, g = lane>>4;
  // col-term bias: 12 registers, loaded once (static indices -> stays in VGPRs)
  float cterm[3][4];
  #pragma unroll
  for (int s=0;s<3;++s)
    #pragma unroll
    for (int q=0;q<4;++q)
      cterm[s][q] = biasv[(g<<2) + q - x + 31 + ((s-1)<<4)];

  // hoisted Q fragments: invariant across the whole column loop
  bf16x8 qa[2][2];
  #pragma unroll
  for (int rt=0;rt<2;++rt){
    int r = (rt<<4) + x;
    #pragma unroll
    for (int hh=0;hh<2;++hh)
      qa[rt][hh] = *(const bf16x8*)&qs[(r<<6) + ((((hh<<2)+g) ^ (r&7))<<3)];
  }

  // phase B: logits -> exp -> P(bf16); flat col-tile loop, 2-deep K prefetch
  float rs[2][4] = {};
  int colW = w<<8;
  const unsigned short* kbase = kg + ((size_t)x<<6) + (g<<3);
  bf16x8 nb0 = *(const bf16x8*)(kbase + ((size_t)colW<<6));
  bf16x8 nb1 = *(const bf16x8*)(kbase + ((size_t)colW<<6) + 32);
  #pragma unroll 2
  for (int t=0; t<16; ++t){
    bf16x8 bk0 = nb0, bk1 = nb1;
    if (t < 15){
      const unsigned short* kp = kbase + ((size_t)(colW + ((t+1)<<4))<<6);
      nb0 = *(const bf16x8*)kp;
      nb1 = *(const bf16x8*)(kp+32);
    }
    int cb = colW + (t<<4);
    int j = cb + x;
    int par = t&1;
    float rterm = biasv[stripe - (cb>>5) + 31];   // wave-uniform row term
    #pragma unroll
    for (int rt=0; rt<2; ++rt){
      f32x4 acc = {};
      acc = MFMA16(qa[rt][0], bk0, acc);
      acc = MFMA16(qa[rt][1], bk1, acc);
      #pragma unroll
      for (int q=0;q<4;++q){
        int r = (rt<<4) + (g<<2) + q;
        float lg = acc[q]*0.125f + rterm + cterm[rt+1-par][q];
        float e = __expf(lg);
        rs[rt][q] += e;
        int byteoff = (r<<11) + ((((j>>3) ^ (r&7)))<<4) + ((j&7)<<1);
        *(unsigned short*)((char*)P + byteoff) = f2bf(e);
      }
    }
  }
  // row sums: butterfly over 16 col-lanes, then cross-wave via LDS
  #pragma unroll
  for (int rt=0;rt<2;++rt){
    #pragma unroll
    for (int q=0;q<4;++q){
      float v = rs[rt][q];
      v += __shfl_xor(v,1); v += __shfl_xor(v,2); v += __shfl_xor(v,4); v += __shfl_xor(v,8);
      if (x==0) rsum[w][(rt<<4)+(g<<2)+q] = v;
    }
  }
  __syncthreads();
  if (tid<32) rinv_s[tid] = 1.f/(rsum[0][tid]+rsum[1][tid]+rsum[2][tid]+rsum[3][tid]);
  __syncthreads();

  // phases C+D interleaved over 8 column-blocks of 128
  float* ao = attn_out + ((size_t)pair<<20) + ((size_t)nbase<<10);
  f32x4 oacc[2] = {};
  int dbase = w<<4;
  const unsigned short* vp = vg + ((size_t)(dbase + x)<<10) + (g<<3);
  for (int cbk=0; cbk<8; ++cbk){
    // C slice: 32 rows x 128 cols
    #pragma unroll
    for (int it=0; it<2; ++it){
      int r = (it<<4) + (tid>>4);
      int c8 = (cbk<<7) + ((tid&15)<<3);
      int byteoff = (r<<11) + ((((c8>>3) ^ (r&7)))<<4);
      bf16x8 pv8 = *(const bf16x8*)((char*)P + byteoff);
      float ri = rinv_s[r];
      float4 o0, o1;
      o0.x = bf2f((unsigned short)pv8[0])*ri;
      o0.y = bf2f((unsigned short)pv8[1])*ri;
      o0.z = bf2f((unsigned short)pv8[2])*ri;
      o0.w = bf2f((unsigned short)pv8[3])*ri;
      o1.x = bf2f((unsigned short)pv8[4])*ri;
      o1.y = bf2f((unsigned short)pv8[5])*ri;
      o1.z = bf2f((unsigned short)pv8[6])*ri;
      o1.w = bf2f((unsigned short)pv8[7])*ri;
      *(float4*)(ao + ((size_t)r<<10) + c8)     = o0;
      *(float4*)(ao + ((size_t)r<<10) + c8 + 4) = o1;
    }
    // D slice: 128 K-steps of PV
    #pragma unroll
    for (int ks=0; ks<4; ++ks){
      int kc = (cbk<<7) + (ks<<5);
      bf16x8 bv = *(const bf16x8*)(vp + kc);
      int ck = (kc>>3) + g;
      #pragma unroll
      for (int rt=0;rt<2;++rt){
        int r = (rt<<4) + x;
        bf16x8 a = *(const bf16x8*)((char*)P + (r<<11) + ((ck ^ (r&7))<<4));
        oacc[rt] = MFMA16(a, bv, oacc[rt]);
      }
    }
  }
  #pragma unroll
  for (int rt=0;rt<2;++rt){
    #pragma unroll
    for (int q=0;q<4;++q){
      int r = (rt<<4) + (g<<2) + q;
      float val = oacc[rt][q]*rinv_s[r];
      oa[((size_t)((bg<<10) + nbase + r)<<10) + (h<<6) + dbase + x] = f2bf(val);
    }
  }
}

extern "C" void kernel_launch(void* const* d_in, const int* in_sizes, int n_in,
                              void* d_out, int out_size, void* d_ws, size_t ws_size,
                              hipStream_t stream)
{
  const float* query = (const float*)d_in[0];
  const float* wi  = (const float*)d_in[3];
  const float* bi  = (const float*)d_in[4];
  const float* wo  = (const float*)d_in[5];
  const float* bo  = (const float*)d_in[6];
  const float* tbl = (const float*)d_in[7];

  char* ws = (char*)d_ws;
  unsigned short* qq  = (unsigned short*)(ws);              // query bf16   8 MB
  unsigned short* wib = (unsigned short*)(ws + 8388608);    // W_in bf16    6 MB
  unsigned short* wob = (unsigned short*)(ws + 14680064);   // W_out bf16   2 MB
  unsigned short* qbf = (unsigned short*)(ws + 16777216);   // q [B,H,N,hd] 8 MB
  unsigned short* kbf = (unsigned short*)(ws + 25165824);   // k [B,H,N,hd] 8 MB
  unsigned short* vTb = (unsigned short*)(ws + 33554432);   // vT [B,H,hd,N] 8 MB
  unsigned short* oa  = (unsigned short*)(ws + 41943040);   // out_attn bf16 8 MB

  float* out  = (float*)d_out;
  float* attn = out + 4194304;

  cast_all<<<dim3(8192), dim3(256), 0, stream>>>(query, wi, wo, qq, wib, wob);
  gemm_qkv<<<dim3(24,32), dim3(256), 0, stream>>>(qq, wib, bi, qbf, kbf, vTb);
  attn_fused<<<dim3(2048), dim3(256), 0, stream>>>(qbf, kbf, vTb, tbl, attn, oa);
  gemm_out<<<dim3(8,32), dim3(512), 0, stream>>>(oa, wob, bo, out);
}